// Round 7
// baseline (187.894 us; speedup 1.0000x reference)
//
#include <hip/hip_runtime.h>
#include <math.h>

#define B_ 2
#define S_ 2048
#define E_ 1024
#define H_ 16
#define DH_ 64
#define NE3_ 3072
#define MTOT_ (B_*S_)
#define QSCALE_ 0.18033688011112042f   // 0.125 * log2(e); P = exp2(s')

typedef __bf16 bf16;
typedef bf16 bf16x8 __attribute__((ext_vector_type(8)));
typedef bf16 bf16x4 __attribute__((ext_vector_type(4)));
typedef float f32x4 __attribute__((ext_vector_type(4)));

#define MFMA16(a,b,c) __builtin_amdgcn_mfma_f32_16x16x32_bf16(a,b,c,0,0,0)

__device__ inline unsigned cvt_pk_bf16(float lo, float hi) {
    unsigned r;
    asm("v_cvt_pk_bf16_f32 %0, %1, %2" : "=v"(r) : "v"(lo), "v"(hi));
    return r;
}

// hardware 2^x: single v_exp_f32
__device__ inline float exp2_hw(float x) {
    float r;
    asm("v_exp_f32 %0, %1" : "=v"(r) : "v"(x));
    return r;
}

__device__ inline void gload_lds16(const void* g, void* l) {
    __builtin_amdgcn_global_load_lds(
        (const __attribute__((address_space(1))) void*)g,
        (__attribute__((address_space(3))) void*)l, 16, 0, 0);
}

// ---------------- fp32 -> bf16 convert, all three arrays in one launch --------
#define NX_ (MTOT_*E_)
#define NW_ (NE3_*E_)
#define NWO_ (E_*E_)
__global__ void k_f2b3(const float* __restrict__ x, const float* __restrict__ wq,
                       const float* __restrict__ wo,
                       bf16* __restrict__ xb, bf16* __restrict__ wqb,
                       bf16* __restrict__ wob) {
    const int i = blockIdx.x * 256 + threadIdx.x;
    const int idx = i * 4;
    const float* src; bf16* dst; int off;
    if (idx < NX_)            { src = x;  dst = xb;  off = idx; }
    else if (idx < NX_ + NW_) { src = wq; dst = wqb; off = idx - NX_; }
    else                      { src = wo; dst = wob; off = idx - NX_ - NW_; }
    float4 f = *reinterpret_cast<const float4*>(src + off);
    bf16x4 o;
    o[0] = (bf16)f.x; o[1] = (bf16)f.y; o[2] = (bf16)f.z; o[3] = (bf16)f.w;
    *reinterpret_cast<bf16x4*>(dst + off) = o;
}

// ---------------- GEMM: C = A @ W^T (+bias), chunk-linear LDS ----------------
// Fragment (chunk C, lane l) at base + C*1024 + l*16.
// A-chunks: C = wr*8 + j*2 + ks -> row wr*64+j*16+(l&15), col-el ks*32+(l>>4)*8.
template<int MODE>
__global__ __launch_bounds__(256) void k_gemm(
    const bf16* __restrict__ A, const bf16* __restrict__ W,
    const float* __restrict__ bias,
    bf16* __restrict__ Qb, bf16* __restrict__ Kb, bf16* __restrict__ Vt,
    float* __restrict__ out)
{
    __shared__ __align__(16) char smem[65536];
    char* Abuf = smem;            // 2 x 16KB
    char* Bbuf = smem + 32768;    // 2 x 16KB
    const int tid = threadIdx.x, lane = tid & 63, w = tid >> 6;
    const int lq = lane & 15, lh = lane >> 4;
    const int l16 = lane * 16;
    const int wr = w >> 1, wc = w & 1;
    const int g = blockIdx.x;
    const int nxw = (MODE == 0 ? 3 : 1);
    const int xcd = g & 7, li = g >> 3;
    const int m0 = (li & 31) * 128;
    const int n0 = (xcd * nxw + (li >> 5)) * 128;

    const int voffA = lq * E_ + lh * 8;   // row-stride 1024 elements

    f32x4 acc[4][4] = {};

    auto stage = [&](int k0, int buf) {
        #pragma unroll
        for (int j = 0; j < 4; ++j) {
            const int C = j*4 + w;
            const int rp = (C>>3)*64 + ((C>>1)&3)*16;
            const int ce = (C&1)*32;
            gload_lds16(A + (size_t)(m0 + rp) * E_ + k0 + ce + (voffA - lq*E_) + lq*E_,
                        Abuf + buf*16384 + C*1024);
            gload_lds16(W + (size_t)(n0 + rp) * E_ + k0 + ce + voffA - lq*E_ + lq*E_,
                        Bbuf + buf*16384 + C*1024);
        }
    };
    // simpler: fold voffA directly
    auto stage2 = [&](int k0, int buf) {
        #pragma unroll
        for (int j = 0; j < 4; ++j) {
            const int C = j*4 + w;
            const int rp = (C>>3)*64 + ((C>>1)&3)*16;
            const int ce = (C&1)*32;
            gload_lds16(A + (size_t)(m0 + rp) * E_ + k0 + ce + voffA,
                        Abuf + buf*16384 + C*1024);
            gload_lds16(W + (size_t)(n0 + rp) * E_ + k0 + ce + voffA,
                        Bbuf + buf*16384 + C*1024);
        }
    };
    stage2(0, 0);
    __syncthreads();

    int cur = 0;
    for (int kt = 0; kt < E_/64; ++kt) {
        if (kt + 1 < E_/64) stage2((kt + 1) * 64, cur ^ 1);
        #pragma unroll
        for (int ks = 0; ks < 2; ++ks) {
            bf16x8 a[4], b[4];
            #pragma unroll
            for (int j = 0; j < 4; ++j)
                a[j] = *(const bf16x8*)(Abuf + cur*16384 + (wr*8 + j*2 + ks)*1024 + l16);
            #pragma unroll
            for (int i = 0; i < 4; ++i)
                b[i] = *(const bf16x8*)(Bbuf + cur*16384 + (wc*8 + i*2 + ks)*1024 + l16);
            #pragma unroll
            for (int i = 0; i < 4; ++i)
                #pragma unroll
                for (int j = 0; j < 4; ++j)
                    acc[i][j] = MFMA16(b[i], a[j], acc[i][j]);
        }
        cur ^= 1;
        if (kt + 1 < E_/64) __syncthreads();
    }

    const int mW = m0 + wr*64;
    for (int i = 0; i < 4; ++i) {
        const int n4 = n0 + wc*64 + i*16 + lh * 4;
        const float4 b4 = *reinterpret_cast<const float4*>(&bias[n4]);
        const float* bp = reinterpret_cast<const float*>(&b4);
        if constexpr (MODE == 0) {
            const int t = n4 >> 10, h = (n4 >> 6) & 15, d0 = n4 & 63;
            for (int j = 0; j < 4; ++j) {
                const int m = mW + j*16 + lq;
                const int bb_i = m >> 11, s = m & 2047;
                if (t == 2) {
                    for (int r = 0; r < 4; ++r)
                        Vt[(((size_t)(bb_i*H_ + h))*DH_ + d0 + r)*S_ + s] =
                            (bf16)(acc[i][j][r] + bp[r]);
                } else {
                    bf16* dst = (t == 0) ? Qb : Kb;
                    const float sc = (t == 0) ? QSCALE_ : 1.0f;
                    bf16x4 o;
                    for (int r = 0; r < 4; ++r)
                        o[r] = (bf16)((acc[i][j][r] + bp[r]) * sc);
                    *reinterpret_cast<bf16x4*>(
                        dst + (((size_t)(bb_i*H_ + h))*S_ + s)*DH_ + d0) = o;
                }
            }
        } else {
            for (int j = 0; j < 4; ++j) {
                const int m = mW + j*16 + lq;
                float4 o;
                o.x = acc[i][j][0] + bp[0];
                o.y = acc[i][j][1] + bp[1];
                o.z = acc[i][j][2] + bp[2];
                o.w = acc[i][j][3] + bp[3];
                *reinterpret_cast<float4*>(out + (size_t)m * E_ + n4) = o;
            }
        }
    }
}

// ---------------- pass 1: l_k = sum_q exp2(S'[q,k]); fold 1/l into V^T -----------
// Kl chunks: C = w*4 + f*2 + ks (row w*32+f*16+lq). Ql chunks: C = qi*2+ks.
__global__ __launch_bounds__(256) void k_colsum(
    const bf16* __restrict__ Qb, const bf16* __restrict__ Kb,
    bf16* __restrict__ Vt)
{
    __shared__ __align__(16) char smem[49152];
    __shared__ float rlbuf[128];
    char* Kl   = smem;            // 16KB
    char* Qbuf = smem + 16384;    // 2 x 16KB
    const int tid = threadIdx.x, lane = tid & 63, w = tid >> 6;
    const int lq = lane & 15, lh = lane >> 4;
    const int l16 = lane * 16;
    const int g = blockIdx.x, xcd = g & 7, li = g >> 3;
    const int bh = xcd * 4 + (li >> 4);
    const int k0 = (li & 15) * 128;
    const bf16* Kbase = Kb + ((size_t)bh * S_ + k0) * DH_;
    const bf16* Qbase = Qb + (size_t)bh * S_ * DH_;
    const int voffK = lq * DH_ + lh * 8;   // row-stride 64 elements

    #pragma unroll
    for (int j = 0; j < 4; ++j) {
        const int C = j*4 + w;
        const int rp = (C>>2)*32 + ((C>>1)&1)*16;
        gload_lds16(Kbase + (size_t)rp * DH_ + (C&1)*32 + voffK, Kl + C*1024);
    }
    auto stageQ = [&](int qt, int buf) {
        #pragma unroll
        for (int j = 0; j < 4; ++j) {
            const int C = j*4 + w;
            gload_lds16(Qbase + (size_t)(qt*128 + (C>>1)*16) * DH_ + (C&1)*32 + voffK,
                        Qbuf + buf*16384 + C*1024);
        }
    };
    stageQ(0, 0);
    __syncthreads();

    bf16x8 bk[2][2];   // [f][ks]: k rows w*32 + f*16 + lq
    #pragma unroll
    for (int f = 0; f < 2; ++f)
        #pragma unroll
        for (int ks = 0; ks < 2; ++ks)
            bk[f][ks] = *(const bf16x8*)(Kl + (w*4 + f*2 + ks)*1024 + l16);

    float lsum0 = 0.f, lsum1 = 0.f;
    int cur = 0;
    for (int qt = 0; qt < S_/128; ++qt) {
        if (qt + 1 < S_/128) stageQ(qt + 1, cur ^ 1);
        #pragma unroll
        for (int qi = 0; qi < 8; ++qi) {
            f32x4 s0 = {}, s1 = {};
            #pragma unroll
            for (int ks = 0; ks < 2; ++ks) {
                bf16x8 aq = *(const bf16x8*)(Qbuf + cur*16384 + (qi*2+ks)*1024 + l16);
                s0 = MFMA16(aq, bk[0][ks], s0);
                s1 = MFMA16(aq, bk[1][ks], s1);
            }
            #pragma unroll
            for (int r = 0; r < 4; ++r) {
                lsum0 += exp2_hw(s0[r]);
                lsum1 += exp2_hw(s1[r]);
            }
        }
        cur ^= 1;
        if (qt + 1 < S_/128) __syncthreads();
    }
    lsum0 += __shfl_xor(lsum0, 16); lsum0 += __shfl_xor(lsum0, 32);
    lsum1 += __shfl_xor(lsum1, 16); lsum1 += __shfl_xor(lsum1, 32);
    if (lane < 16) {
        rlbuf[w*32 + lane]      = 1.0f / lsum0;
        rlbuf[w*32 + 16 + lane] = 1.0f / lsum1;
    }
    __syncthreads();

    bf16* Vb = Vt + (size_t)bh * DH_ * S_ + k0;
    const int d = tid >> 2, kk = (tid & 3) * 32;
    for (int c = 0; c < 4; ++c) {
        bf16x8* p = reinterpret_cast<bf16x8*>(Vb + (size_t)d * S_ + kk + c*8);
        bf16x8 v = *p, o;
        for (int jj = 0; jj < 8; ++jj)
            o[jj] = (bf16)((float)v[jj] * rlbuf[kk + c*8 + jj]);
        *p = o;
    }
}

// ---------------- pass 2: O = exp2(S') @ V'; chunk-linear everything ----------
// K chunks: C = kf*2+ks. V chunks: C = df*2+ks. Q chunks (per wave): qi*2+ks.
// P chunks (per wave): ks*2+qi, read linear; write via pOff + immediates.
__global__ __launch_bounds__(256) void k_attn(
    const bf16* __restrict__ Qb, const bf16* __restrict__ Kb,
    const bf16* __restrict__ Vt, bf16* __restrict__ AO)
{
    __shared__ __align__(16) char smem[49152];
    char* QP   = smem;            // 16KB Q -> per-wave P after hoist
    char* Kbuf = smem + 16384;    // 2 x 8KB
    char* Vbuf = smem + 32768;    // 2 x 8KB
    const int tid = threadIdx.x, lane = tid & 63, w = tid >> 6;
    const int lq = lane & 15, lh = lane >> 4;
    const int l16 = lane * 16;
    const int g = blockIdx.x, xcd = g & 7, li = g >> 3;
    const int bh = xcd * 4 + (li >> 4);
    const int q0 = (li & 15) * 128;
    const bf16* Qbase = Qb + ((size_t)bh * S_ + q0) * DH_;
    const bf16* Kbase = Kb + (size_t)bh * S_ * DH_;
    const bf16* Vbase = Vt + (size_t)bh * DH_ * S_;
    char* Plw = QP + w * 4096;
    const int voffK = lq * DH_ + lh * 8;     // K/Q row-stride 64
    const int voffV = lq * S_ + lh * 8;      // V^T row-stride 2048
    // P write lane offset: slot ((lh>>1)*16 + lq)*16 + (lh&1)*8
    const int pOff = (lh >> 1) * 256 + lq * 16 + (lh & 1) * 8;

    // stage Q: 16 chunks (consumer wave = C>>2, qi = (C>>1)&1, ks = C&1)
    #pragma unroll
    for (int j = 0; j < 4; ++j) {
        const int C = j*4 + w;
        const int rp = (C>>2)*32 + ((C>>1)&1)*16;
        gload_lds16(Qbase + (size_t)rp * DH_ + (C&1)*32 + voffK, QP + C*1024);
    }
    auto stageKV = [&](int kt, int buf) {
        #pragma unroll
        for (int j = 0; j < 2; ++j) {
            const int C = j*4 + w;
            gload_lds16(Kbase + (size_t)(kt*64 + (C>>1)*16) * DH_ + (C&1)*32 + voffK,
                        Kbuf + buf*8192 + C*1024);
            gload_lds16(Vbase + (size_t)((C>>1)*16) * S_ + kt*64 + (C&1)*32 + voffV,
                        Vbuf + buf*8192 + C*1024);
        }
    };
    stageKV(0, 0);
    __syncthreads();

    // hoist Q fragments (wave-private chunks)
    bf16x8 bq[2][2];
    #pragma unroll
    for (int qi = 0; qi < 2; ++qi)
        #pragma unroll
        for (int ks = 0; ks < 2; ++ks)
            bq[qi][ks] = *(const bf16x8*)(QP + w*4096 + (qi*2+ks)*1024 + l16);

    f32x4 oacc[4][2] = {};
    int cur = 0;
    for (int kt = 0; kt < S_/64; ++kt) {
        if (kt + 1 < S_/64) stageKV(kt + 1, cur ^ 1);
        char* Kc = Kbuf + cur*8192;
        char* Vc = Vbuf + cur*8192;

        // swapped QK^T; P = exp2(s') -> chunk-linear Plw
        #pragma unroll
        for (int kf = 0; kf < 4; ++kf) {
            f32x4 sacc[2] = {};
            #pragma unroll
            for (int ks = 0; ks < 2; ++ks) {
                bf16x8 ak = *(const bf16x8*)(Kc + (kf*2+ks)*1024 + l16);
                #pragma unroll
                for (int qi = 0; qi < 2; ++qi)
                    sacc[qi] = MFMA16(ak, bq[qi][ks], sacc[qi]);
            }
            #pragma unroll
            for (int qi = 0; qi < 2; ++qi) {
                uint2 pw;
                pw.x = cvt_pk_bf16(exp2_hw(sacc[qi][0]), exp2_hw(sacc[qi][1]));
                pw.y = cvt_pk_bf16(exp2_hw(sacc[qi][2]), exp2_hw(sacc[qi][3]));
                *(uint2*)(Plw + pOff + (kf>>1)*2048 + (kf&1)*512 + qi*1024) = pw;
            }
        }

        // PV: all reads linear (base + imm + l16)
        #pragma unroll
        for (int ks = 0; ks < 2; ++ks) {
            bf16x8 av[4], bp[2];
            #pragma unroll
            for (int df = 0; df < 4; ++df)
                av[df] = *(const bf16x8*)(Vc + (df*2+ks)*1024 + l16);
            #pragma unroll
            for (int qi = 0; qi < 2; ++qi)
                bp[qi] = *(const bf16x8*)(Plw + (ks*2+qi)*1024 + l16);
            #pragma unroll
            for (int df = 0; df < 4; ++df)
                #pragma unroll
                for (int qi = 0; qi < 2; ++qi)
                    oacc[df][qi] = MFMA16(av[df], bp[qi], oacc[df][qi]);
        }
        cur ^= 1;
        if (kt + 1 < S_/64) __syncthreads();
    }

    // epilogue: AO[b, q, h*64+d], 4 consecutive d -> 8B stores
    const int b = bh >> 4, h = bh & 15;
    #pragma unroll
    for (int df = 0; df < 4; ++df)
        #pragma unroll
        for (int qi = 0; qi < 2; ++qi) {
            const int d0 = df*16 + lh * 4;
            const int q = q0 + w*32 + qi*16 + lq;
            bf16x4 o;
            for (int r = 0; r < 4; ++r) o[r] = (bf16)oacc[df][qi][r];
            *reinterpret_cast<bf16x4*>(
                AO + ((size_t)(b*S_ + q))*E_ + h*DH_ + d0) = o;
        }
}

extern "C" void kernel_launch(void* const* d_in, const int* in_sizes, int n_in,
                              void* d_out, int out_size, void* d_ws, size_t ws_size,
                              hipStream_t stream) {
    const float* input = (const float*)d_in[0];
    const float* Wqkv  = (const float*)d_in[1];
    const float* bqkv  = (const float*)d_in[2];
    const float* Wo    = (const float*)d_in[3];
    const float* bo    = (const float*)d_in[4];
    float* out = (float*)d_out;

    char* ws = (char*)d_ws;
    bf16*  Xb   = (bf16*) (ws + 0);
    bf16*  Wqb  = (bf16*) (ws + 8388608);
    bf16*  Wob  = (bf16*) (ws + 14680064);
    bf16*  Qb   = (bf16*) (ws + 16777216);
    bf16*  Kb   = (bf16*) (ws + 25165824);
    bf16*  Vtg  = (bf16*) (ws + 33554432);
    bf16*  AO   = (bf16*) (ws + 41943040);

    k_f2b3<<<(NX_ + NW_ + NWO_) / 1024, 256, 0, stream>>>(
        input, Wqkv, Wo, Xb, Wqb, Wob);

    k_gemm<0><<<768, 256, 0, stream>>>(Xb, Wqb, bqkv, Qb, Kb, Vtg, nullptr);

    k_colsum<<<512, 256, 0, stream>>>(Qb, Kb, Vtg);

    k_attn<<<512, 256, 0, stream>>>(Qb, Kb, Vtg, AO);

    k_gemm<1><<<256, 256, 0, stream>>>(AO, Wob, bo, nullptr, nullptr, nullptr, out);
}

// Round 8
// 168.244 us; speedup vs baseline: 1.1168x; 1.1168x over previous
//
#include <hip/hip_runtime.h>
#include <math.h>

#define B_ 2
#define S_ 2048
#define E_ 1024
#define H_ 16
#define DH_ 64
#define NE3_ 3072
#define MTOT_ (B_*S_)
#define QSCALE_ 0.18033688011112042f   // 0.125 * log2(e); P = exp2(s')

typedef __bf16 bf16;
typedef bf16 bf16x8 __attribute__((ext_vector_type(8)));
typedef bf16 bf16x4 __attribute__((ext_vector_type(4)));
typedef float f32x4 __attribute__((ext_vector_type(4)));

#define MFMA16(a,b,c) __builtin_amdgcn_mfma_f32_16x16x32_bf16(a,b,c,0,0,0)

// XOR swizzle: rows are 128B; slot = 16B unit.
#define F_(r) ((((r) & 7) ^ (((r) >> 3) & 7)))

__device__ inline void* lds_swz(void* base, int row, int bytecol) {
    return (char*)base + row * 128 + (bytecol ^ (F_(row) << 4));
}

__device__ inline unsigned cvt_pk_bf16(float lo, float hi) {
    unsigned r;
    asm("v_cvt_pk_bf16_f32 %0, %1, %2" : "=v"(r) : "v"(lo), "v"(hi));
    return r;
}

// hardware 2^x: single v_exp_f32
__device__ inline float exp2_hw(float x) {
    float r;
    asm("v_exp_f32 %0, %1" : "=v"(r) : "v"(x));
    return r;
}

__device__ inline void gload_lds16(const void* g, void* l) {
    __builtin_amdgcn_global_load_lds(
        (const __attribute__((address_space(1))) void*)g,
        (__attribute__((address_space(3))) void*)l, 16, 0, 0);
}

// ---------------- fp32 -> bf16 convert, all three arrays in one launch --------
#define NX_ (MTOT_*E_)
#define NW_ (NE3_*E_)
#define NWO_ (E_*E_)
__global__ void k_f2b3(const float* __restrict__ x, const float* __restrict__ wq,
                       const float* __restrict__ wo,
                       bf16* __restrict__ xb, bf16* __restrict__ wqb,
                       bf16* __restrict__ wob) {
    const int i = blockIdx.x * 256 + threadIdx.x;
    const int idx = i * 4;
    const float* src; bf16* dst; int off;
    if (idx < NX_)            { src = x;  dst = xb;  off = idx; }
    else if (idx < NX_ + NW_) { src = wq; dst = wqb; off = idx - NX_; }
    else                      { src = wo; dst = wob; off = idx - NX_ - NW_; }
    float4 f = *reinterpret_cast<const float4*>(src + off);
    bf16x4 o;
    o[0] = (bf16)f.x; o[1] = (bf16)f.y; o[2] = (bf16)f.z; o[3] = (bf16)f.w;
    *reinterpret_cast<bf16x4*>(dst + off) = o;
}

// ---------------- GEMM: C = A @ W^T (+bias), swapped orientation ----------------
// MODE 0: single-buffered LDS (32KB, m97-style) -> 3 blocks/CU at grid 768.
// MODE 1: double-buffered (grid 256 = 1 block/CU; dbuf is the only overlap).
template<int MODE>
__global__ __launch_bounds__(256) void k_gemm(
    const bf16* __restrict__ A, const bf16* __restrict__ W,
    const float* __restrict__ bias,
    bf16* __restrict__ Qb, bf16* __restrict__ Kb, bf16* __restrict__ Vt,
    float* __restrict__ out)
{
    constexpr int NBUF = (MODE == 0) ? 1 : 2;
    __shared__ __align__(16) bf16 At[NBUF][128*64];
    __shared__ __align__(16) bf16 Bt[NBUF][128*64];
    const int tid = threadIdx.x, lane = tid & 63, w = tid >> 6;
    const int wr = w >> 1, wc = w & 1;
    const int g = blockIdx.x;
    const int nxw = (MODE == 0 ? 3 : 1);
    const int xcd = g & 7, li = g >> 3;
    const int m0 = (li & 31) * 128;
    const int n0 = (xcd * nxw + (li >> 5)) * 128;

    f32x4 acc[4][4] = {};
    const int lrow = lane >> 3, lcol = (lane & 7) * 8;

    auto stage = [&](int k0, int buf) {
        for (int c4 = 0; c4 < 4; ++c4) {
            const int c = w * 4 + c4;
            const int row = c * 8 + lrow;
            const int colx = lcol ^ (F_(row) * 8);
            gload_lds16(A + (size_t)(m0 + row) * E_ + k0 + colx, &At[buf][c * 512]);
            gload_lds16(W + (size_t)(n0 + row) * E_ + k0 + colx, &Bt[buf][c * 512]);
        }
    };
    auto compute = [&](int buf) {
        for (int ks = 0; ks < 2; ++ks) {
            const int bc = ks * 64 + 16 * (lane >> 4);
            bf16x8 a[4], b[4];
            for (int j = 0; j < 4; ++j)
                a[j] = *(const bf16x8*)lds_swz(&At[buf][0], wr*64 + j*16 + (lane&15), bc);
            for (int i = 0; i < 4; ++i)
                b[i] = *(const bf16x8*)lds_swz(&Bt[buf][0], wc*64 + i*16 + (lane&15), bc);
            for (int i = 0; i < 4; ++i)
                for (int j = 0; j < 4; ++j)
                    acc[i][j] = MFMA16(b[i], a[j], acc[i][j]);
        }
    };

    if constexpr (MODE == 0) {
        // m97-style single buffer: cross-block wave overlap does the pipelining
        stage(0, 0);
        __syncthreads();
        for (int kt = 0; kt < E_/64; ++kt) {
            compute(0);
            if (kt + 1 < E_/64) {
                __syncthreads();
                stage((kt + 1) * 64, 0);
                __syncthreads();
            }
        }
    } else {
        stage(0, 0);
        __syncthreads();
        int cur = 0;
        for (int kt = 0; kt < E_/64; ++kt) {
            if (kt + 1 < E_/64) stage((kt + 1) * 64, cur ^ 1);
            compute(cur);
            cur ^= 1;
            if (kt + 1 < E_/64) __syncthreads();
        }
    }

    const int mW = m0 + wr*64;
    for (int i = 0; i < 4; ++i) {
        const int n4 = n0 + wc*64 + i*16 + (lane >> 4) * 4;
        const float4 b4 = *reinterpret_cast<const float4*>(&bias[n4]);
        const float* bp = reinterpret_cast<const float*>(&b4);
        if constexpr (MODE == 0) {
            const int t = n4 >> 10, h = (n4 >> 6) & 15, d0 = n4 & 63;
            for (int j = 0; j < 4; ++j) {
                const int m = mW + j*16 + (lane & 15);
                const int bb_i = m >> 11, s = m & 2047;
                if (t == 2) {
                    for (int r = 0; r < 4; ++r)
                        Vt[(((size_t)(bb_i*H_ + h))*DH_ + d0 + r)*S_ + s] =
                            (bf16)(acc[i][j][r] + bp[r]);
                } else {
                    bf16* dst = (t == 0) ? Qb : Kb;
                    const float sc = (t == 0) ? QSCALE_ : 1.0f;
                    bf16x4 o;
                    for (int r = 0; r < 4; ++r)
                        o[r] = (bf16)((acc[i][j][r] + bp[r]) * sc);
                    *reinterpret_cast<bf16x4*>(
                        dst + (((size_t)(bb_i*H_ + h))*S_ + s)*DH_ + d0) = o;
                }
            }
        } else {
            for (int j = 0; j < 4; ++j) {
                const int m = mW + j*16 + (lane & 15);
                float4 o;
                o.x = acc[i][j][0] + bp[0];
                o.y = acc[i][j][1] + bp[1];
                o.z = acc[i][j][2] + bp[2];
                o.w = acc[i][j][3] + bp[3];
                *reinterpret_cast<float4*>(out + (size_t)m * E_ + n4) = o;
            }
        }
    }
}

// ---------------- pass 1: l_k = sum_q exp2(S'[q,k]); fold 1/l into V^T -----------
__global__ __launch_bounds__(256) void k_colsum(
    const bf16* __restrict__ Qb, const bf16* __restrict__ Kb,
    bf16* __restrict__ Vt)
{
    __shared__ __align__(16) bf16 Kl[128*64];
    __shared__ __align__(16) bf16 Ql[2][128*64];
    __shared__ float rlbuf[128];
    const int tid = threadIdx.x, lane = tid & 63, w = tid >> 6;
    const int g = blockIdx.x, xcd = g & 7, li = g >> 3;
    const int bh = xcd * 4 + (li >> 4);
    const int k0 = (li & 15) * 128;
    const bf16* Kbase = Kb + ((size_t)bh * S_ + k0) * DH_;
    const bf16* Qbase = Qb + (size_t)bh * S_ * DH_;

    for (int j = 0; j < 4; ++j) {
        const int idx = j*256 + tid, row = idx >> 3;
        const int colx = ((idx & 7) * 8) ^ (F_(row) * 8);
        gload_lds16(Kbase + (size_t)row * DH_ + colx, &Kl[(j*256 + w*64) * 8]);
    }
    auto stageQ = [&](int qt, int buf) {
        for (int j = 0; j < 4; ++j) {
            const int idx = j*256 + tid, row = idx >> 3;
            const int colx = ((idx & 7) * 8) ^ (F_(row) * 8);
            gload_lds16(Qbase + (size_t)(qt*128 + row) * DH_ + colx,
                        &Ql[buf][(j*256 + w*64) * 8]);
        }
    };
    stageQ(0, 0);
    __syncthreads();

    bf16x8 bk[2][2];
    for (int ks = 0; ks < 2; ++ks) {
        const int bc = ks * 64 + 16 * (lane >> 4);
        bk[ks][0] = *(const bf16x8*)lds_swz(Kl, w*32 + (lane&15), bc);
        bk[ks][1] = *(const bf16x8*)lds_swz(Kl, w*32 + 16 + (lane&15), bc);
    }

    float lsum0 = 0.f, lsum1 = 0.f;
    int cur = 0;
    for (int qt = 0; qt < S_/128; ++qt) {
        if (qt + 1 < S_/128) stageQ(qt + 1, cur ^ 1);
        #pragma unroll
        for (int qi = 0; qi < 8; ++qi) {
            f32x4 s0 = {}, s1 = {};
            for (int ks = 0; ks < 2; ++ks) {
                const int bc = ks * 64 + 16 * (lane >> 4);
                bf16x8 aq = *(const bf16x8*)lds_swz(&Ql[cur][0], qi*16 + (lane&15), bc);
                s0 = MFMA16(aq, bk[ks][0], s0);
                s1 = MFMA16(aq, bk[ks][1], s1);
            }
            for (int r = 0; r < 4; ++r) {
                lsum0 += exp2_hw(s0[r]);
                lsum1 += exp2_hw(s1[r]);
            }
        }
        cur ^= 1;
        if (qt + 1 < S_/128) __syncthreads();
    }
    lsum0 += __shfl_xor(lsum0, 16); lsum0 += __shfl_xor(lsum0, 32);
    lsum1 += __shfl_xor(lsum1, 16); lsum1 += __shfl_xor(lsum1, 32);
    if (lane < 16) {
        rlbuf[w*32 + lane]      = 1.0f / lsum0;
        rlbuf[w*32 + 16 + lane] = 1.0f / lsum1;
    }
    __syncthreads();

    bf16* Vb = Vt + (size_t)bh * DH_ * S_ + k0;
    const int d = tid >> 2, kk = (tid & 3) * 32;
    for (int c = 0; c < 4; ++c) {
        bf16x8* p = reinterpret_cast<bf16x8*>(Vb + (size_t)d * S_ + kk + c*8);
        bf16x8 v = *p, o;
        for (int jj = 0; jj < 8; ++jj)
            o[jj] = (bf16)((float)v[jj] * rlbuf[kk + c*8 + jj]);
        *p = o;
    }
}

// ---------------- pass 2: O = exp2(S') @ V'; 128q blocks, 32 q/wave ----------
__global__ __launch_bounds__(256) void k_attn(
    const bf16* __restrict__ Qb, const bf16* __restrict__ Kb,
    const bf16* __restrict__ Vt, bf16* __restrict__ AO)
{
    // [0,16384) Ql (128 rows x 128B) -> per-wave Pl after hoist
    // [16384,32768) Kl dbuf; [32768,49152) Vl dbuf
    __shared__ __align__(16) char smem[49152];
    const int tid = threadIdx.x, lane = tid & 63, w = tid >> 6;
    const int g = blockIdx.x, xcd = g & 7, li = g >> 3;
    const int bh = xcd * 4 + (li >> 4);
    const int q0 = (li & 15) * 128;
    const bf16* Qbase = Qb + ((size_t)bh * S_ + q0) * DH_;
    const bf16* Kbase = Kb + (size_t)bh * S_ * DH_;
    const bf16* Vbase = Vt + (size_t)bh * DH_ * S_;
    char* QP  = smem;
    char* Plw = smem + w * 4096;   // wave w's 32 Q rows == its Pl region

    // stage Q (128 rows x 64 dh)
    for (int j = 0; j < 4; ++j) {
        const int idx = j*256 + tid, row = idx >> 3;
        const int colx = ((idx & 7) * 8) ^ (F_(row) * 8);
        gload_lds16(Qbase + (size_t)row * DH_ + colx, QP + (j*256 + w*64) * 16);
    }
    auto stageKV = [&](int kt, int buf) {
        for (int j = 0; j < 2; ++j) {
            const int idx = j*256 + tid, row = idx >> 3;
            const int colx = ((idx & 7) * 8) ^ (F_(row) * 8);
            gload_lds16(Kbase + (size_t)(kt*64 + row) * DH_ + colx,
                        smem + 16384 + buf*8192 + (j*256 + w*64) * 16);
            gload_lds16(Vbase + (size_t)row * S_ + kt*64 + colx,
                        smem + 32768 + buf*8192 + (j*256 + w*64) * 16);
        }
    };
    stageKV(0, 0);
    __syncthreads();

    // hoist Q fragments: bq[qi][ks] -> 16 VGPRs (wave-private rows)
    bf16x8 bq[2][2];
    for (int qi = 0; qi < 2; ++qi)
        for (int ks = 0; ks < 2; ++ks)
            bq[qi][ks] = *(const bf16x8*)lds_swz(QP, w*32 + qi*16 + (lane&15),
                                                 ks*64 + 16*(lane>>4));

    f32x4 oacc[4][2] = {};
    int cur = 0;
    for (int kt = 0; kt < S_/64; ++kt) {
        if (kt + 1 < S_/64) stageKV(kt + 1, cur ^ 1);
        char* Kc = smem + 16384 + cur*8192;
        char* Vc = smem + 32768 + cur*8192;

        // swapped QK^T, kf-sliced; P = exp2(s') -> Plw [32q][64k]
        for (int kf = 0; kf < 4; ++kf) {
            f32x4 sacc[2] = {};
            for (int ks = 0; ks < 2; ++ks) {
                bf16x8 ak = *(const bf16x8*)lds_swz(Kc, kf*16 + (lane&15),
                                                    ks*64 + 16*(lane>>4));
                for (int qi = 0; qi < 2; ++qi)
                    sacc[qi] = MFMA16(ak, bq[qi][ks], sacc[qi]);
            }
            for (int qi = 0; qi < 2; ++qi) {
                uint2 pw;
                pw.x = cvt_pk_bf16(exp2_hw(sacc[qi][0]), exp2_hw(sacc[qi][1]));
                pw.y = cvt_pk_bf16(exp2_hw(sacc[qi][2]), exp2_hw(sacc[qi][3]));
                *(uint2*)lds_swz(Plw, qi*16 + (lane&15), kf*32 + (lane>>4)*8) = pw;
            }
        }

        // PV: O^T[64d][32q] += V'-tile @ P^T (4x2 register blocking)
        for (int ks = 0; ks < 2; ++ks) {
            const int bc = ks*64 + 16*(lane>>4);
            bf16x8 av[4], bp[2];
            for (int df = 0; df < 4; ++df)
                av[df] = *(const bf16x8*)lds_swz(Vc, df*16 + (lane&15), bc);
            for (int qi = 0; qi < 2; ++qi)
                bp[qi] = *(const bf16x8*)lds_swz(Plw, qi*16 + (lane&15), bc);
            for (int df = 0; df < 4; ++df)
                for (int qi = 0; qi < 2; ++qi)
                    oacc[df][qi] = MFMA16(av[df], bp[qi], oacc[df][qi]);
        }
        cur ^= 1;
        if (kt + 1 < S_/64) __syncthreads();
    }

    // epilogue: AO[b, q, h*64+d], 4 consecutive d -> 8B stores
    const int b = bh >> 4, h = bh & 15;
    for (int df = 0; df < 4; ++df)
        for (int qi = 0; qi < 2; ++qi) {
            const int d0 = df*16 + (lane >> 4) * 4;
            const int q = q0 + w*32 + qi*16 + (lane & 15);
            bf16x4 o;
            for (int r = 0; r < 4; ++r) o[r] = (bf16)oacc[df][qi][r];
            *reinterpret_cast<bf16x4*>(
                AO + ((size_t)(b*S_ + q))*E_ + h*DH_ + d0) = o;
        }
}

extern "C" void kernel_launch(void* const* d_in, const int* in_sizes, int n_in,
                              void* d_out, int out_size, void* d_ws, size_t ws_size,
                              hipStream_t stream) {
    const float* input = (const float*)d_in[0];
    const float* Wqkv  = (const float*)d_in[1];
    const float* bqkv  = (const float*)d_in[2];
    const float* Wo    = (const float*)d_in[3];
    const float* bo    = (const float*)d_in[4];
    float* out = (float*)d_out;

    char* ws = (char*)d_ws;
    bf16*  Xb   = (bf16*) (ws + 0);
    bf16*  Wqb  = (bf16*) (ws + 8388608);
    bf16*  Wob  = (bf16*) (ws + 14680064);
    bf16*  Qb   = (bf16*) (ws + 16777216);
    bf16*  Kb   = (bf16*) (ws + 25165824);
    bf16*  Vtg  = (bf16*) (ws + 33554432);
    bf16*  AO   = (bf16*) (ws + 41943040);

    k_f2b3<<<(NX_ + NW_ + NWO_) / 1024, 256, 0, stream>>>(
        input, Wqkv, Wo, Xb, Wqb, Wob);

    k_gemm<0><<<768, 256, 0, stream>>>(Xb, Wqb, bqkv, Qb, Kb, Vtg, nullptr);

    k_colsum<<<512, 256, 0, stream>>>(Qb, Kb, Vtg);

    k_attn<<<512, 256, 0, stream>>>(Qb, Kb, Vtg, AO);

    k_gemm<1><<<256, 256, 0, stream>>>(AO, Wob, bo, nullptr, nullptr, nullptr, out);
}

// Round 9
// 158.564 us; speedup vs baseline: 1.1850x; 1.0610x over previous
//
#include <hip/hip_runtime.h>
#include <math.h>

#define B_ 2
#define S_ 2048
#define E_ 1024
#define H_ 16
#define DH_ 64
#define NE3_ 3072
#define MTOT_ (B_*S_)
#define QSCALE_ 0.18033688011112042f   // 0.125 * log2(e); P = exp2(s')

typedef __bf16 bf16;
typedef bf16 bf16x8 __attribute__((ext_vector_type(8)));
typedef bf16 bf16x4 __attribute__((ext_vector_type(4)));
typedef float f32x4 __attribute__((ext_vector_type(4)));

#define MFMA16(a,b,c) __builtin_amdgcn_mfma_f32_16x16x32_bf16(a,b,c,0,0,0)

// XOR swizzle for row-major staging (GEMM inputs only)
#define F_(r) ((((r) & 7) ^ (((r) >> 3) & 7)))

__device__ inline void* lds_swz(void* base, int row, int bytecol) {
    return (char*)base + row * 128 + (bytecol ^ (F_(row) << 4));
}

__device__ inline unsigned cvt_pk_bf16(float lo, float hi) {
    unsigned r;
    asm("v_cvt_pk_bf16_f32 %0, %1, %2" : "=v"(r) : "v"(lo), "v"(hi));
    return r;
}

__device__ inline float exp2_hw(float x) {
    float r;
    asm("v_exp_f32 %0, %1" : "=v"(r) : "v"(x));
    return r;
}

__device__ inline void gload_lds16(const void* g, void* l) {
    __builtin_amdgcn_global_load_lds(
        (const __attribute__((address_space(1))) void*)g,
        (__attribute__((address_space(3))) void*)l, 16, 0, 0);
}

// ---------------- fp32 -> bf16 convert, all three arrays in one launch --------
#define NX_ (MTOT_*E_)
#define NW_ (NE3_*E_)
#define NWO_ (E_*E_)
__global__ void k_f2b3(const float* __restrict__ x, const float* __restrict__ wq,
                       const float* __restrict__ wo,
                       bf16* __restrict__ xb, bf16* __restrict__ wqb,
                       bf16* __restrict__ wob) {
    const int i = blockIdx.x * 256 + threadIdx.x;
    const int idx = i * 4;
    const float* src; bf16* dst; int off;
    if (idx < NX_)            { src = x;  dst = xb;  off = idx; }
    else if (idx < NX_ + NW_) { src = wq; dst = wqb; off = idx - NX_; }
    else                      { src = wo; dst = wob; off = idx - NX_ - NW_; }
    float4 f = *reinterpret_cast<const float4*>(src + off);
    bf16x4 o;
    o[0] = (bf16)f.x; o[1] = (bf16)f.y; o[2] = (bf16)f.z; o[3] = (bf16)f.w;
    *reinterpret_cast<bf16x4*>(dst + off) = o;
}

// ---------------- GEMM: C = A @ W^T (+bias), swapped orientation ----------------
// MODE 0: epilogue -> FRAGMENT-MAJOR Qf/Kf/Vf: [bh][tile64][chunk8][lane64][e8]
//   Q/K fragment: chunk = kf*2+ks, elem(row kf*16+lq', col ks*32+lh'*8+e), Q *QSCALE
//   V  fragment: chunk = df*2+ks, row d = df*16+lq', col k = ks*32+lh'*8+e
// MODE 1: fp32 d_out, float4 stores.
template<int MODE>
__global__ __launch_bounds__(256) void k_gemm(
    const bf16* __restrict__ A, const bf16* __restrict__ W,
    const float* __restrict__ bias,
    bf16* __restrict__ Qf, bf16* __restrict__ Kf, bf16* __restrict__ Vf,
    float* __restrict__ out)
{
    constexpr int NBUF = (MODE == 0) ? 1 : 2;
    __shared__ __align__(16) bf16 At[NBUF][128*64];
    __shared__ __align__(16) bf16 Bt[NBUF][128*64];
    const int tid = threadIdx.x, lane = tid & 63, w = tid >> 6;
    const int lq = lane & 15, lh = lane >> 4;
    const int wr = w >> 1, wc = w & 1;
    const int g = blockIdx.x;
    const int nxw = (MODE == 0 ? 3 : 1);
    const int xcd = g & 7, li = g >> 3;
    const int m0 = (li & 31) * 128;
    const int n0 = (xcd * nxw + (li >> 5)) * 128;

    f32x4 acc[4][4] = {};
    const int lrow = lane >> 3, lcol = (lane & 7) * 8;

    auto stage = [&](int k0, int buf) {
        for (int c4 = 0; c4 < 4; ++c4) {
            const int c = w * 4 + c4;
            const int row = c * 8 + lrow;
            const int colx = lcol ^ (F_(row) * 8);
            gload_lds16(A + (size_t)(m0 + row) * E_ + k0 + colx, &At[buf][c * 512]);
            gload_lds16(W + (size_t)(n0 + row) * E_ + k0 + colx, &Bt[buf][c * 512]);
        }
    };
    auto compute = [&](int buf) {
        for (int ks = 0; ks < 2; ++ks) {
            const int bc = ks * 64 + 16 * lh;
            bf16x8 a[4], b[4];
            for (int j = 0; j < 4; ++j)
                a[j] = *(const bf16x8*)lds_swz(&At[buf][0], wr*64 + j*16 + lq, bc);
            for (int i = 0; i < 4; ++i)
                b[i] = *(const bf16x8*)lds_swz(&Bt[buf][0], wc*64 + i*16 + lq, bc);
            for (int i = 0; i < 4; ++i)
                for (int j = 0; j < 4; ++j)
                    acc[i][j] = MFMA16(b[i], a[j], acc[i][j]);
        }
    };

    if constexpr (MODE == 0) {
        stage(0, 0);
        __syncthreads();
        for (int kt = 0; kt < E_/64; ++kt) {
            compute(0);
            if (kt + 1 < E_/64) {
                __syncthreads();
                stage((kt + 1) * 64, 0);
                __syncthreads();
            }
        }
    } else {
        stage(0, 0);
        __syncthreads();
        int cur = 0;
        for (int kt = 0; kt < E_/64; ++kt) {
            if (kt + 1 < E_/64) stage((kt + 1) * 64, cur ^ 1);
            compute(cur);
            cur ^= 1;
            if (kt + 1 < E_/64) __syncthreads();
        }
    }

    const int mW = m0 + wr*64;
    for (int i = 0; i < 4; ++i) {
        const int n4 = n0 + wc*64 + i*16 + lh * 4;
        const float4 b4 = *reinterpret_cast<const float4*>(&bias[n4]);
        const float* bp = reinterpret_cast<const float*>(&b4);
        if constexpr (MODE == 0) {
            const int t = n4 >> 10, h = (n4 >> 6) & 15, d0 = n4 & 63;
            for (int j = 0; j < 4; ++j) {
                const int m = mW + j*16 + lq;
                const int bb_i = m >> 11, s = m & 2047;
                const size_t bh32 = ((size_t)(bb_i*H_ + h)) * 32;
                const int kt = s >> 6;
                if (t == 2) {
                    // V fragment: scalar scatter (d varies per r)
                    const int ksV = (s >> 5) & 1, lhV = (s >> 3) & 3, eV = s & 7;
                    for (int r = 0; r < 4; ++r) {
                        const int d = d0 + r;
                        const size_t e = ((bh32 + kt)*8 + (d>>4)*2 + ksV)*512
                                       + (lhV*16 + (d & 15))*8 + eV;
                        Vf[e] = (bf16)(acc[i][j][r] + bp[r]);
                    }
                } else {
                    // Q/K fragment: 4 consecutive elems -> 8B store
                    bf16* dst = (t == 0) ? Qf : Kf;
                    const float sc = (t == 0) ? QSCALE_ : 1.0f;
                    const int kf = (s >> 4) & 3, lqp = s & 15;
                    const size_t e = ((bh32 + kt)*8 + kf*2 + (d0>>5))*512
                                   + (((d0>>3)&3)*16 + lqp)*8 + (d0 & 7);
                    bf16x4 o;
                    for (int r = 0; r < 4; ++r)
                        o[r] = (bf16)((acc[i][j][r] + bp[r]) * sc);
                    *reinterpret_cast<bf16x4*>(dst + e) = o;
                }
            }
        } else {
            for (int j = 0; j < 4; ++j) {
                const int m = mW + j*16 + lq;
                float4 o;
                o.x = acc[i][j][0] + bp[0];
                o.y = acc[i][j][1] + bp[1];
                o.z = acc[i][j][2] + bp[2];
                o.w = acc[i][j][3] + bp[3];
                *reinterpret_cast<float4*>(out + (size_t)m * E_ + n4) = o;
            }
        }
    }
}

// ---------------- pass 1: l_k = sum_q exp2(S'[q,k]); fold 1/l into Vf -----------
// All tiles fragment-major: staging fully contiguous, LDS chunk-linear.
__global__ __launch_bounds__(256) void k_colsum(
    const bf16* __restrict__ Qf, const bf16* __restrict__ Kf,
    bf16* __restrict__ Vf)
{
    __shared__ __align__(16) char smem[49152];
    __shared__ float rlbuf[128];
    char* Kl   = smem;            // 16KB (128 k rows)
    char* Qbuf = smem + 16384;    // 2 x 16KB
    const int tid = threadIdx.x, lane = tid & 63, w = tid >> 6;
    const int l16 = lane * 16;
    const int g = blockIdx.x, xcd = g & 7, li = g >> 3;
    const int bh = xcd * 4 + (li >> 4);
    const int k0 = (li & 15) * 128;
    const bf16* Kbase = Kf + ((size_t)bh*32 + (k0 >> 6)) * 4096;
    const bf16* Qbase = Qf + (size_t)bh*32 * 4096;

    for (int j = 0; j < 4; ++j)
        gload_lds16(Kbase + (j*256 + tid)*8, Kl + (j*256 + w*64)*16);
    auto stageQ = [&](int qt, int buf) {
        const bf16* qb = Qbase + (size_t)qt * 8192;
        for (int j = 0; j < 4; ++j)
            gload_lds16(qb + (j*256 + tid)*8, Qbuf + buf*16384 + (j*256 + w*64)*16);
    };
    stageQ(0, 0);
    __syncthreads();

    bf16x8 bk[2][2];   // [f][ks]: k rows w*32 + f*16 + lq
    for (int f = 0; f < 2; ++f)
        for (int ks = 0; ks < 2; ++ks)
            bk[f][ks] = *(const bf16x8*)(Kl + (w*4 + f*2 + ks)*1024 + l16);

    float lsum0 = 0.f, lsum1 = 0.f;
    int cur = 0;
    for (int qt = 0; qt < S_/128; ++qt) {
        if (qt + 1 < S_/128) stageQ(qt + 1, cur ^ 1);
        #pragma unroll
        for (int qi = 0; qi < 8; ++qi) {
            f32x4 s0 = {}, s1 = {};
            #pragma unroll
            for (int ks = 0; ks < 2; ++ks) {
                bf16x8 aq = *(const bf16x8*)(Qbuf + cur*16384 + (qi*2+ks)*1024 + l16);
                s0 = MFMA16(aq, bk[0][ks], s0);
                s1 = MFMA16(aq, bk[1][ks], s1);
            }
            #pragma unroll
            for (int r = 0; r < 4; ++r) {
                lsum0 += exp2_hw(s0[r]);
                lsum1 += exp2_hw(s1[r]);
            }
        }
        cur ^= 1;
        if (qt + 1 < S_/128) __syncthreads();
    }
    lsum0 += __shfl_xor(lsum0, 16); lsum0 += __shfl_xor(lsum0, 32);
    lsum1 += __shfl_xor(lsum1, 16); lsum1 += __shfl_xor(lsum1, 32);
    if (lane < 16) {
        rlbuf[w*32 + lane]      = 1.0f / lsum0;
        rlbuf[w*32 + 16 + lane] = 1.0f / lsum1;
    }
    __syncthreads();

    // scale Vf fragments for k in [k0, k0+128): 16KB contiguous, k derivable
    bf16* Vb = Vf + ((size_t)bh*32 + (k0 >> 6)) * 4096;
    for (int c = 0; c < 4; ++c) {
        const int v = c*256 + tid;               // vec8 index, 0..1023
        const int kb = (v >> 9)*64 + ((v >> 6) & 1)*32 + ((v >> 4) & 3)*8;
        bf16x8* p = reinterpret_cast<bf16x8*>(Vb + v*8);
        bf16x8 x = *p, o;
        #pragma unroll
        for (int jj = 0; jj < 8; ++jj)
            o[jj] = (bf16)((float)x[jj] * rlbuf[kb + jj]);
        *p = o;
    }
}

// ---------------- pass 2: O = exp2(S') @ V'; all chunk-linear ----------
__global__ __launch_bounds__(256) void k_attn(
    const bf16* __restrict__ Qf, const bf16* __restrict__ Kf,
    const bf16* __restrict__ Vf, bf16* __restrict__ AO)
{
    __shared__ __align__(16) char smem[49152];
    char* QP   = smem;            // 16KB Q -> per-wave P after hoist
    char* Kbuf = smem + 16384;    // 2 x 8KB
    char* Vbuf = smem + 32768;    // 2 x 8KB
    const int tid = threadIdx.x, lane = tid & 63, w = tid >> 6;
    const int lq = lane & 15, lh = lane >> 4;
    const int l16 = lane * 16;
    const int g = blockIdx.x, xcd = g & 7, li = g >> 3;
    const int bh = xcd * 4 + (li >> 4);
    const int q0 = (li & 15) * 128;
    const bf16* Qbase = Qf + ((size_t)bh*32 + (q0 >> 6)) * 4096;
    const bf16* KVof  = (const bf16*)0;
    const bf16* Kbase = Kf + (size_t)bh*32 * 4096;
    const bf16* Vbase = Vf + (size_t)bh*32 * 4096;
    char* Plw = QP + w * 4096;
    // P write lane offset (verified r7): slot ((lh>>1)*16+lq)*16 + (lh&1)*8
    const int pOff = (lh >> 1) * 256 + lq * 16 + (lh & 1) * 8;

    for (int j = 0; j < 4; ++j)
        gload_lds16(Qbase + (j*256 + tid)*8, QP + (j*256 + w*64)*16);
    auto stageKV = [&](int kt, int buf) {
        const bf16* kb = Kbase + (size_t)kt * 4096;
        const bf16* vb = Vbase + (size_t)kt * 4096;
        for (int j = 0; j < 2; ++j) {
            gload_lds16(kb + (j*256 + tid)*8, Kbuf + buf*8192 + (j*256 + w*64)*16);
            gload_lds16(vb + (j*256 + tid)*8, Vbuf + buf*8192 + (j*256 + w*64)*16);
        }
    };
    stageKV(0, 0);
    __syncthreads();

    // hoist Q fragments: per-wave chunks at QP + w*4096
    bf16x8 bq[2][2];
    for (int qi = 0; qi < 2; ++qi)
        for (int ks = 0; ks < 2; ++ks)
            bq[qi][ks] = *(const bf16x8*)(QP + w*4096 + (qi*2+ks)*1024 + l16);

    f32x4 oacc[4][2] = {};
    int cur = 0;
    for (int kt = 0; kt < S_/64; ++kt) {
        if (kt + 1 < S_/64) stageKV(kt + 1, cur ^ 1);
        char* Kc = Kbuf + cur*8192;
        char* Vc = Vbuf + cur*8192;

        // swapped QK^T; P = exp2(s') -> chunk-linear Plw
        #pragma unroll
        for (int kf = 0; kf < 4; ++kf) {
            f32x4 sacc[2] = {};
            #pragma unroll
            for (int ks = 0; ks < 2; ++ks) {
                bf16x8 ak = *(const bf16x8*)(Kc + (kf*2+ks)*1024 + l16);
                #pragma unroll
                for (int qi = 0; qi < 2; ++qi)
                    sacc[qi] = MFMA16(ak, bq[qi][ks], sacc[qi]);
            }
            #pragma unroll
            for (int qi = 0; qi < 2; ++qi) {
                uint2 pw;
                pw.x = cvt_pk_bf16(exp2_hw(sacc[qi][0]), exp2_hw(sacc[qi][1]));
                pw.y = cvt_pk_bf16(exp2_hw(sacc[qi][2]), exp2_hw(sacc[qi][3]));
                *(uint2*)(Plw + pOff + (kf>>1)*2048 + (kf&1)*512 + qi*1024) = pw;
            }
        }

        // PV: all reads linear
        #pragma unroll
        for (int ks = 0; ks < 2; ++ks) {
            bf16x8 av[4], bp[2];
            #pragma unroll
            for (int df = 0; df < 4; ++df)
                av[df] = *(const bf16x8*)(Vc + (df*2+ks)*1024 + l16);
            #pragma unroll
            for (int qi = 0; qi < 2; ++qi)
                bp[qi] = *(const bf16x8*)(Plw + (ks*2+qi)*1024 + l16);
            #pragma unroll
            for (int df = 0; df < 4; ++df)
                #pragma unroll
                for (int qi = 0; qi < 2; ++qi)
                    oacc[df][qi] = MFMA16(av[df], bp[qi], oacc[df][qi]);
        }
        cur ^= 1;
        if (kt + 1 < S_/64) __syncthreads();
    }

    // epilogue: AO[b, q, h*64+d], 4 consecutive d -> 8B stores
    const int b = bh >> 4, h = bh & 15;
    #pragma unroll
    for (int df = 0; df < 4; ++df)
        #pragma unroll
        for (int qi = 0; qi < 2; ++qi) {
            const int d0 = df*16 + lh * 4;
            const int q = q0 + w*32 + qi*16 + lq;
            bf16x4 o;
            for (int r = 0; r < 4; ++r) o[r] = (bf16)oacc[df][qi][r];
            *reinterpret_cast<bf16x4*>(
                AO + ((size_t)(b*S_ + q))*E_ + h*DH_ + d0) = o;
        }
}

extern "C" void kernel_launch(void* const* d_in, const int* in_sizes, int n_in,
                              void* d_out, int out_size, void* d_ws, size_t ws_size,
                              hipStream_t stream) {
    const float* input = (const float*)d_in[0];
    const float* Wqkv  = (const float*)d_in[1];
    const float* bqkv  = (const float*)d_in[2];
    const float* Wo    = (const float*)d_in[3];
    const float* bo    = (const float*)d_in[4];
    float* out = (float*)d_out;

    char* ws = (char*)d_ws;
    bf16*  Xb   = (bf16*) (ws + 0);
    bf16*  Wqb  = (bf16*) (ws + 8388608);
    bf16*  Wob  = (bf16*) (ws + 14680064);
    bf16*  Qfg  = (bf16*) (ws + 16777216);
    bf16*  Kfg  = (bf16*) (ws + 25165824);
    bf16*  Vfg  = (bf16*) (ws + 33554432);
    bf16*  AO   = (bf16*) (ws + 41943040);

    k_f2b3<<<(NX_ + NW_ + NWO_) / 1024, 256, 0, stream>>>(
        input, Wqkv, Wo, Xb, Wqb, Wob);

    k_gemm<0><<<768, 256, 0, stream>>>(Xb, Wqb, bqkv, Qfg, Kfg, Vfg, nullptr);

    k_colsum<<<512, 256, 0, stream>>>(Qfg, Kfg, Vfg);

    k_attn<<<512, 256, 0, stream>>>(Qfg, Kfg, Vfg, AO);

    k_gemm<1><<<256, 256, 0, stream>>>(AO, Wob, bo, nullptr, nullptr, nullptr, out);
}